// Round 3
// baseline (624.474 us; speedup 1.0000x reference)
//
#include <hip/hip_runtime.h>

#define Bn 512
#define Ln 2048
#define Kn 19
#define NEGV (-1000.0f)
#define START_IDn 17
#define PAD_IDn 18
#define SEG 64               // checkpoint segment (steps)
#define PBYTES 79691776u     // 512*2048*19*4

// ---------------------------------------------------------------------------
// R8: crf_fwd broadcast moved OFF the DS pipe. dp[0..15] is distributed with a
// 15-instruction XOR-DPP butterfly (row_mirror=^15, half_mirror=^7, their
// composition=^8, quad_perm=^1/^2/^3 => all 16 masks), all direction-free
// semantics. Tags 16..18 (incl. START=17) live as lane-replicated regs g0..g2,
// recomputed per step by a secondary accumulator on lanes jr<3 and re-broadcast
// by 3 sixteen-lane-local ds_swizzles whose ~120cy latency overlaps the NEXT
// step's VALU network (off-chain). Emissions stream from global (depth-8 ring,
// vmcnt-decoupled). 4 batches per wave (DPP rows independent). Exact reference
// pairings dp[k]+T[j][k], exact-max trees => checkpoints bit-identical; rec/bwd
// unchanged.
// ---------------------------------------------------------------------------

// crf_rec per-step core (unchanged): dp read from LDS, occupancy hides it.
#define DP_CORE(BASE)                                                          \
    float4 q0 = *(const float4*)((BASE) + 0);                                  \
    float4 q1 = *(const float4*)((BASE) + 4);                                  \
    float4 q2 = *(const float4*)((BASE) + 8);                                  \
    float4 q3 = *(const float4*)((BASE) + 12);                                 \
    float4 q4 = *(const float4*)((BASE) + 16); /* .w junk, unused */           \
    float cand[Kn];                                                            \
    cand[0]  = q0.x + Trow[0];  cand[1]  = q0.y + Trow[1];                     \
    cand[2]  = q0.z + Trow[2];  cand[3]  = q0.w + Trow[3];                     \
    cand[4]  = q1.x + Trow[4];  cand[5]  = q1.y + Trow[5];                     \
    cand[6]  = q1.z + Trow[6];  cand[7]  = q1.w + Trow[7];                     \
    cand[8]  = q2.x + Trow[8];  cand[9]  = q2.y + Trow[9];                     \
    cand[10] = q2.z + Trow[10]; cand[11] = q2.w + Trow[11];                    \
    cand[12] = q3.x + Trow[12]; cand[13] = q3.y + Trow[13];                    \
    cand[14] = q3.z + Trow[14]; cand[15] = q3.w + Trow[15];                    \
    cand[16] = q4.x + Trow[16]; cand[17] = q4.y + Trow[17];                    \
    cand[18] = q4.z + Trow[18];                                                \
    float m0 = fmaxf(fmaxf(cand[0],  cand[1]),  cand[2]);                      \
    float m1 = fmaxf(fmaxf(cand[3],  cand[4]),  cand[5]);                      \
    float m2 = fmaxf(fmaxf(cand[6],  cand[7]),  cand[8]);                      \
    float m3 = fmaxf(fmaxf(cand[9],  cand[10]), cand[11]);                     \
    float m4 = fmaxf(fmaxf(cand[12], cand[13]), cand[14]);                     \
    float m5 = fmaxf(fmaxf(cand[15], cand[16]), cand[17]);                     \
    float n0 = fmaxf(fmaxf(m0, m1), m2);                                       \
    float n1 = fmaxf(fmaxf(m3, m4), cand[18]);                                 \
    float best = fmaxf(fmaxf(n0, n1), m5);

// DPP permute: result[lane] = x[perm(lane)], all lanes enabled, row-local.
#define DPPF(x, ctrl) (__int_as_float(__builtin_amdgcn_update_dpp(            \
    __float_as_int(x), __float_as_int(x), (ctrl), 0xF, 0xF, false)))
// 16-lane-local broadcast from group-lane (base16 | i): offset=(i<<5)|0x10.
#define SWZF(x, off) (__int_as_float(__builtin_amdgcn_ds_swizzle(             \
    __float_as_int(x), (off))))

// max over 16 butterfly candidates (v0..vf + TT[m]) and 3 trio cands (g+GT).
#define TREE19(RES, TT, GT)                                                    \
    {                                                                          \
      float d0 = v0 + TT[0],  d1 = v1 + TT[1],  d2 = v2 + TT[2];               \
      float d3 = v3 + TT[3],  d4 = v4 + TT[4],  d5 = v5 + TT[5];               \
      float d6 = v6 + TT[6],  d7 = v7 + TT[7],  d8 = v8 + TT[8];               \
      float d9 = v9 + TT[9],  d10 = va + TT[10], d11 = vb + TT[11];            \
      float d12 = vc + TT[12], d13 = vd + TT[13], d14 = ve + TT[14];           \
      float d15 = vf + TT[15];                                                 \
      float e16 = g0 + GT[0], e17 = g1 + GT[1], e18 = g2 + GT[2];              \
      float m0 = fmaxf(fmaxf(d0, d1), d2);                                     \
      float m1 = fmaxf(fmaxf(d3, d4), d5);                                     \
      float m2 = fmaxf(fmaxf(d6, d7), d8);                                     \
      float m3 = fmaxf(fmaxf(d9, d10), d11);                                   \
      float m4 = fmaxf(fmaxf(d12, d13), d14);                                  \
      float m5 = fmaxf(fmaxf(d15, e16), e17);                                  \
      float n0 = fmaxf(fmaxf(m0, m1), m2);                                     \
      float n1 = fmaxf(fmaxf(m3, m4), m5);                                     \
      RES = fmaxf(fmaxf(n0, n1), e18);                                         \
    }

// One DP step. v_m[lane] = A[lane^m] via XOR-DPP network:
//   bases: ^0 (A), ^7 (half_mirror 0x141), ^15 (mirror 0x140), ^8 (hm(mirror))
//   quad_perm: ^1 = 0xB1 [1,0,3,2], ^2 = 0x4E [2,3,0,1], ^3 = 0x1B [3,2,1,0]
#define FSTEP(U, MASKED)                                                       \
  {                                                                            \
    const int t = t0 + tt + (U);                                               \
    const float v0 = A;                                                        \
    const float v1 = DPPF(A, 0xB1);                                            \
    const float v2 = DPPF(A, 0x4E);                                            \
    const float v3 = DPPF(A, 0x1B);                                            \
    const float v7 = DPPF(A, 0x141);                                           \
    const float v6 = DPPF(v7, 0xB1);                                           \
    const float v5 = DPPF(v7, 0x4E);                                           \
    const float v4 = DPPF(v7, 0x1B);                                           \
    const float vf = DPPF(A, 0x140);                                           \
    const float ve = DPPF(vf, 0xB1);                                           \
    const float vd = DPPF(vf, 0x4E);                                           \
    const float vc = DPPF(vf, 0x1B);                                           \
    const float v8 = DPPF(vf, 0x141);                                          \
    const float v9 = DPPF(v8, 0xB1);                                           \
    const float va = DPPF(v8, 0x4E);                                           \
    const float vb = DPPF(v8, 0x1B);                                           \
    float bp, bs;                                                              \
    TREE19(bp, Tp, Gp)                                                         \
    TREE19(bs, Ts, Gs)                                                         \
    const float nd  = bp + eb[(U)];                                            \
    const float nd2 = bs + eb2[(U)];                                           \
    if (MASKED) {                                                              \
      A   = (t < len) ? nd  : A;                                               \
      sec = (t < len) ? nd2 : sec;                                             \
    } else {                                                                   \
      A   = nd;                                                                \
      sec = nd2;                                                               \
    }                                                                          \
    g0 = SWZF(sec, 0x10);                                                      \
    g1 = SWZF(sec, 0x30);                                                      \
    g2 = SWZF(sec, 0x50);                                                      \
    int tn = t + 8;                                                            \
    tn = (tn < Ln) ? tn : (Ln - 1);                                            \
    eb[(U)]  = prow[tn * Kn + jr];                                             \
    eb2[(U)] = prow[tn * Kn + o2];                                             \
  }

// ---------------------------------------------------------------------------
__global__ __launch_bounds__(64, 1) void crf_fwd(
    const float* __restrict__ P, const float* __restrict__ T,
    const int* __restrict__ mask, float* __restrict__ dpck,
    float* __restrict__ dpfin, int* __restrict__ lens)
{
    const int lane = threadIdx.x;
    const int jr = lane & 15;             // tag 0..15 (primary output)
    const int row = lane >> 4;            // 0..3: four batches per wave
    const int b = blockIdx.x * 4 + row;
    const int o2 = 16 + ((jr < 3) ? jr : 2);   // secondary output tag (clamped)

    // pre-baked transition rows, butterfly-indexed: Tp[m] = T[jr][jr^m]
    float Tp[16], Ts[16], Gp[3], Gs[3];
#pragma unroll
    for (int m = 0; m < 16; ++m) {
        Tp[m] = T[jr * Kn + (jr ^ m)];
        Ts[m] = T[o2 * Kn + (jr ^ m)];
    }
#pragma unroll
    for (int i = 0; i < 3; ++i) {
        Gp[i] = T[jr * Kn + 16 + i];
        Gs[i] = T[o2 * Kn + 16 + i];
    }

    // length = popcount of contiguous-prefix mask row (16 lanes per batch)
    const int* mrow = mask + (size_t)b * Ln;
    int sum = 0;
#pragma unroll
    for (int j2 = 0; j2 < 32; ++j2) {
        int4 v = *(const int4*)(mrow + j2 * 64 + jr * 4);
        sum += v.x + v.y + v.z + v.w;
    }
    sum += __shfl_xor(sum, 1, 64);
    sum += __shfl_xor(sum, 2, 64);
    sum += __shfl_xor(sum, 4, 64);
    sum += __shfl_xor(sum, 8, 64);
    const int len = sum;                  // per-row (batch) length
    if (jr == 0) lens[b] = len;
    int lx = len, ln_ = len;
    { int u16a = __shfl_xor(lx, 16, 64); lx = lx > u16a ? lx : u16a;
      int u16b = __shfl_xor(ln_, 16, 64); ln_ = ln_ < u16b ? ln_ : u16b; }
    { int u32a = __shfl_xor(lx, 32, 64); lx = lx > u32a ? lx : u32a;
      int u32b = __shfl_xor(ln_, 32, 64); ln_ = ln_ < u32b ? ln_ : u32b; }
    const int lmin = __builtin_amdgcn_readfirstlane(ln_);
    const int mlen = (__builtin_amdgcn_readfirstlane(lx) + (SEG - 1)) & ~(SEG - 1);

    // DP state: A = dp[jr] (per row); sec = dp[16+jr] on jr<3; g* replicated trio
    float A = NEGV;                                   // tags 0..15 start NEG
    float sec = (jr == 1) ? 0.0f : NEGV;              // tag 17 == START -> 0
    float g0 = NEGV, g1 = 0.0f, g2 = NEGV;            // dp[16],dp[17],dp[18]

    // emission ring (depth 8), straight from global (L2/L3-cached, read-once)
    const float* prow = P + (size_t)b * Ln * Kn;
    float eb[8], eb2[8];
#pragma unroll
    for (int u = 0; u < 8; ++u) {
        eb[u]  = prow[u * Kn + jr];
        eb2[u] = prow[u * Kn + o2];
    }

    for (int t0 = 0; t0 < mlen; t0 += SEG) {
        // checkpoint: DP entering step t0 (includes initial DP at t0=0)
        {
            const unsigned ck = ((unsigned)b * 32u + (unsigned)(t0 >> 6)) * (unsigned)Kn;
            dpck[ck + (unsigned)jr] = A;
            if (jr < 3) dpck[ck + 16u + (unsigned)jr] = sec;
        }
        if (t0 + SEG <= lmin) {
            for (int tt = 0; tt < SEG; tt += 8) {
                FSTEP(0, 0) FSTEP(1, 0) FSTEP(2, 0) FSTEP(3, 0)
                FSTEP(4, 0) FSTEP(5, 0) FSTEP(6, 0) FSTEP(7, 0)
            }
        } else {
            for (int tt = 0; tt < SEG; tt += 8) {
                FSTEP(0, 1) FSTEP(1, 1) FSTEP(2, 1) FSTEP(3, 1)
                FSTEP(4, 1) FSTEP(5, 1) FSTEP(6, 1) FSTEP(7, 1)
            }
        }
    }
    dpfin[b * Kn + jr] = A;
    if (jr < 3) dpfin[b * Kn + 16 + jr] = sec;
}

// ---------------------------------------------------------------------------
// Recompute backpointers: task = (batch, segment); 32-lane half-wave per task,
// 8 tasks per 256-thread block. High occupancy hides all latencies; per-step
// math is bit-identical to crf_fwd (same add pairs, max exact), so argmax
// reproduces the exact backpointers of a fully-serial run.
// ---------------------------------------------------------------------------
__global__ __launch_bounds__(256) void crf_rec(
    const float* __restrict__ P, const float* __restrict__ T,
    const float* __restrict__ dpck, const int* __restrict__ lens,
    unsigned char* __restrict__ choice)
{
    const int tid = threadIdx.x;
    const int halfid = tid >> 5;
    const int c = tid & 31;
    const int cc = (c < Kn) ? c : (Kn - 1);
    const int task = blockIdx.x * 8 + halfid;   // < 16384
    const int b = task >> 5;
    const int seg = task & 31;
    const int t0 = seg * SEG;
    const int len = lens[b];
    if (t0 >= len) return;                      // rows never read by backtrace

    __shared__ float dp[8][32];
    __shared__ __align__(16) unsigned char cbuf[8][SEG * Kn];  // 8 x 1216

    float Trow[Kn];
#pragma unroll
    for (int p = 0; p < Kn; ++p) Trow[p] = T[cc * Kn + p];

    float mydp = (c < Kn) ? dpck[((unsigned)b * 32u + (unsigned)seg) * (unsigned)Kn + (unsigned)c]
                          : NEGV;
    dp[halfid][c] = mydp;

    const float* prow = P + (size_t)b * Ln * Kn + (size_t)t0 * Kn;

    // rolling emission prefetch (depth 8)
    float eb[8];
#pragma unroll
    for (int u = 0; u < 8; ++u) eb[u] = prow[u * Kn + cc];

    for (int tt = 0; tt < SEG; tt += 8) {
#pragma unroll
        for (int u = 0; u < 8; ++u) {
            const int t = t0 + tt + u;
            const float e = eb[u];
            const float* base_ = &dp[halfid][0];
            DP_CORE(base_)
            float nd = best + e;
            mydp = (t < len) ? nd : mydp;
            dp[halfid][c] = mydp;

            // first-index argmax (jnp.argmax tie-break), exact equality
            int arg = Kn - 1;
#pragma unroll
            for (int p = Kn - 2; p >= 0; --p)
                arg = (cand[p] == best) ? p : arg;
            if (c < Kn) cbuf[halfid][(tt + u) * Kn + c] = (unsigned char)arg;

            // prefetch emission for local step tt+u+8 (clamped in-bounds)
            int tn = tt + u + 8;
            int tloc = (t0 + tn < Ln) ? tn : (Ln - 1 - t0);
            eb[u] = prow[tloc * Kn + cc];
        }
    }
    // bulk flush this segment's backpointers (steps >= len garbage, unread)
    {
        const int4* s = (const int4*)&cbuf[halfid][0];
        int4* d = (int4*)(choice + (size_t)b * Ln * Kn + (size_t)t0 * Kn);
        for (int i = c; i < (SEG * Kn) / 16; i += 32) d[i] = s[i];
    }
}

// ---------------------------------------------------------------------------
// Backtrace: unchanged (exact integer function-composition scan).
// ---------------------------------------------------------------------------
__global__ __launch_bounds__(384, 1) void crf_bwd(
    const float* __restrict__ T, const unsigned char* __restrict__ choice,
    const float* __restrict__ dpfin, const int* __restrict__ lens,
    int* __restrict__ out)
{
    __shared__ unsigned char comp[Ln * Kn];   // 38912 B
    __shared__ int vchain[17];
    __shared__ int s_last, s_len;

    const int b = blockIdx.x;
    const int tid = threadIdx.x;

    {
        const int4* src = (const int4*)(choice + (size_t)b * Ln * Kn);
        int4* dst = (int4*)comp;
        for (int i = tid; i < (Ln * Kn) / 16; i += 384) dst[i] = src[i];
    }
    if (tid == 0) {
        s_len = lens[b];
        float bestv = dpfin[b * Kn + 0] + T[PAD_IDn * Kn + 0];
        int bl = 0;
        for (int ci = 1; ci < Kn; ++ci) {
            float v = dpfin[b * Kn + ci] + T[PAD_IDn * Kn + ci];
            if (v > bestv) { bestv = v; bl = ci; }
        }
        s_last = bl;
    }
    __syncthreads();
    const int len = s_len;

    // Phase 1: suffix-compose within each 128-step chunk, in place.
    // Rows t >= len compose to identity (g_t = id), so garbage in those
    // choice rows is read-then-discarded, never propagated.
    {
        const int wv = tid >> 6;
        const int lane = tid & 63;
        const int ch = wv * 3 + lane / Kn;
        const int c = lane % Kn;
        if (lane < 3 * Kn && ch < 16) {
            int cur = c;
            const int tb = ch * 128 + 127;
            for (int i = 0; i < 128; ++i) {
                const int t = tb - i;
                int nv = comp[t * Kn + cur];   // cur <= 18 always: in-bounds
                cur = (t < len) ? nv : cur;
                comp[t * Kn + c] = cur;
            }
        }
    }
    __syncthreads();

    // Phase 2: chunk-boundary chain
    if (tid == 0) {
        int v = s_last;
        vchain[16] = v;
        for (int ch = 15; ch >= 0; --ch) {
            v = comp[ch * 128 * Kn + v];
            vchain[ch] = v;
        }
    }
    __syncthreads();

    // Phase 3: emit path
    const int last = s_last;
    int* orow = out + (size_t)b * Ln;
    for (int t = tid; t < Ln; t += 384) {
        int val;
        if (t >= len) {
            val = -1;
        } else if (t == Ln - 1) {
            val = last;
        } else {
            const int tp = t + 1;
            const int vc = vchain[(tp >> 7) + 1];
            val = comp[tp * Kn + vc];
        }
        orow[t] = val;
    }
}

// ---------------------------------------------------------------------------
extern "C" void kernel_launch(void* const* d_in, const int* in_sizes, int n_in,
                              void* d_out, int out_size, void* d_ws, size_t ws_size,
                              hipStream_t stream)
{
    const float* P    = (const float*)d_in[0];
    const float* T    = (const float*)d_in[1];
    const int*   mask = (const int*)d_in[2];
    int* out = (int*)d_out;

    // workspace layout — identical footprint to R1-R3 (19,963,904 B proven ok)
    const size_t choice_bytes = (size_t)Bn * Ln * Kn;            // 19,922,944
    unsigned char* choice = (unsigned char*)d_ws;
    float* dpfin = (float*)((char*)d_ws + choice_bytes);         // 38,912 B
    int* lens = (int*)((char*)d_ws + choice_bytes + (size_t)Bn * Kn * 4);

    // dpck (1,245,184 B) lives in d_out (4 MB): written by crf_fwd, read by
    // crf_rec, then d_out is fully overwritten by crf_bwd. Stream-ordered.
    float* dpck = (float*)((char*)d_out + 2 * 1024 * 1024);

    crf_fwd<<<Bn / 4, 64, 0, stream>>>(P, T, mask, dpck, dpfin, lens);
    crf_rec<<<(Bn * 32) / 8, 256, 0, stream>>>(P, T, dpck, lens, choice);
    crf_bwd<<<Bn, 384, 0, stream>>>(T, choice, dpfin, lens, out);
}

// Round 4
// 411.248 us; speedup vs baseline: 1.5185x; 1.5185x over previous
//
#include <hip/hip_runtime.h>

#define Bn 512
#define Ln 2048
#define Kn 19
#define NEGV (-1000.0f)
#define START_IDn 17
#define PAD_IDn 18
#define SEG 64               // checkpoint segment (steps)
#define PBYTES 79691776u     // 512*2048*19*4

// ---------------------------------------------------------------------------
// R9: producer-consumer fusion. The R5 fwd wave (proven 238us, 280cy/step
// floor; R6/R7/R8 alternatives all measured worse) runs unchanged as wave 0.
// Waves 1-2 are trailing rec engines (4 half-wave engines) that consume
// per-segment DP checkpoints from LDS, gated by a volatile seg_done flag
// (single writer, DS-pipe in-order per wave), recompute the segment with the
// BIT-IDENTICAL DP_CORE op order, and write backpointers. rec's ~140us is
// thereby hidden under fwd's 98%-idle 238us. dpck global buffer + crf_rec
// kernel deleted. crf_bwd unchanged.
// ---------------------------------------------------------------------------

// Per-step core (shared, bit-exact op order): cand[p] = dp[p] + Trow[p],
// best = exact max tree.
#define DP_CORE(BASE)                                                          \
    float4 q0 = *(const float4*)((BASE) + 0);                                  \
    float4 q1 = *(const float4*)((BASE) + 4);                                  \
    float4 q2 = *(const float4*)((BASE) + 8);                                  \
    float4 q3 = *(const float4*)((BASE) + 12);                                 \
    float4 q4 = *(const float4*)((BASE) + 16); /* .w junk, unused */           \
    float cand[Kn];                                                            \
    cand[0]  = q0.x + Trow[0];  cand[1]  = q0.y + Trow[1];                     \
    cand[2]  = q0.z + Trow[2];  cand[3]  = q0.w + Trow[3];                     \
    cand[4]  = q1.x + Trow[4];  cand[5]  = q1.y + Trow[5];                     \
    cand[6]  = q1.z + Trow[6];  cand[7]  = q1.w + Trow[7];                     \
    cand[8]  = q2.x + Trow[8];  cand[9]  = q2.y + Trow[9];                     \
    cand[10] = q2.z + Trow[10]; cand[11] = q2.w + Trow[11];                    \
    cand[12] = q3.x + Trow[12]; cand[13] = q3.y + Trow[13];                    \
    cand[14] = q3.z + Trow[14]; cand[15] = q3.w + Trow[15];                    \
    cand[16] = q4.x + Trow[16]; cand[17] = q4.y + Trow[17];                    \
    cand[18] = q4.z + Trow[18];                                                \
    float m0 = fmaxf(fmaxf(cand[0],  cand[1]),  cand[2]);                      \
    float m1 = fmaxf(fmaxf(cand[3],  cand[4]),  cand[5]);                      \
    float m2 = fmaxf(fmaxf(cand[6],  cand[7]),  cand[8]);                      \
    float m3 = fmaxf(fmaxf(cand[9],  cand[10]), cand[11]);                     \
    float m4 = fmaxf(fmaxf(cand[12], cand[13]), cand[14]);                     \
    float m5 = fmaxf(fmaxf(cand[15], cand[16]), cand[17]);                     \
    float n0 = fmaxf(fmaxf(m0, m1), m2);                                       \
    float n1 = fmaxf(fmaxf(m3, m4), cand[18]);                                 \
    float best = fmaxf(fmaxf(n0, n1), m5);

// ---------------------------------------------------------------------------
__global__ __launch_bounds__(192, 1) void crf_fused(
    const float* __restrict__ P, const float* __restrict__ T,
    const int* __restrict__ mask, float* __restrict__ dpfin,
    int* __restrict__ lens, unsigned char* __restrict__ choice)
{
    const int tid = threadIdx.x;
    const int w = tid >> 6;              // wave 0 = fwd; waves 1,2 = rec

    // --- shared state -------------------------------------------------------
    __shared__ float dp[2][32];                    // fwd DP round-trip
    __shared__ float ebuf[2][2][1280];             // fwd emission staging
    __shared__ float ckbuf[2][32][20];             // checkpoints [half][seg][tag]
    __shared__ int   s_len2[2];
    __shared__ int   seg_done[2];                  // #checkpoints written per half
    __shared__ float rdp[2][2][32];                // rec DP [recwave][half][tag]
    __shared__ __align__(16) unsigned char rcbuf[2][2][1280];  // rec bp staging

    if (tid < 2) *(volatile int*)&seg_done[tid] = 0;
    __syncthreads();                               // all 3 waves reach once

    if (w == 0) {
        // ===================== FWD wave (R5-identical core) =================
        __builtin_amdgcn_s_setprio(1);             // win issue arbitration
        const int lane = tid;
        const int half = lane >> 5;
        const int c = lane & 31;
        const int b = blockIdx.x * 2 + half;
        const int cc = (c < Kn) ? c : (Kn - 1);

        float Trow[Kn];
#pragma unroll
        for (int p = 0; p < Kn; ++p) Trow[p] = T[cc * Kn + p];

        // length = popcount of contiguous-prefix mask row
        const int* mrow = mask + (size_t)b * Ln;
        int sum = 0;
#pragma unroll
        for (int j = 0; j < Ln / 128; ++j) {
            int4 v = *(const int4*)(mrow + j * 128 + c * 4);
            sum += v.x + v.y + v.z + v.w;
        }
#pragma unroll
        for (int k = 1; k < 32; k <<= 1) sum += __shfl_xor(sum, k, 64);
        const int len = sum;
        if (c == 0) { lens[b] = len; s_len2[half] = len; }
        const int lenO = __shfl_xor(len, 32, 64);
        int maxlen = len > lenO ? len : lenO;
        int lmin = len < lenO ? len : lenO;
        lmin = __builtin_amdgcn_readfirstlane(lmin);
        int mlen = (maxlen + (SEG - 1)) & ~(SEG - 1);
        mlen = __builtin_amdgcn_readfirstlane(mlen);

        float mydp = (c == START_IDn) ? 0.0f : NEGV;
        dp[half][c] = mydp;

        const unsigned bbyte = (unsigned)b * (Ln * Kn * 4u);
        const unsigned limit = PBYTES - 16;
        const char* Pc = (const char*)P;
        float4 r[10];

#define STAGE_LOAD(ci)                                                         \
    { unsigned base_ = bbyte + (unsigned)(ci) * 4864u + ((unsigned)c << 4);    \
      _Pragma("unroll")                                                        \
      for (int i_ = 0; i_ < 10; ++i_) {                                        \
          unsigned o_ = base_ + (unsigned)i_ * 512u;                           \
          if (o_ > limit) o_ = limit;                                          \
          r[i_] = *(const float4*)(Pc + o_);                                   \
      } }
#define STAGE_WRITE(nb)                                                        \
    { float* d_ = &ebuf[nb][half][(unsigned)c << 2];                           \
      _Pragma("unroll")                                                        \
      for (int i_ = 0; i_ < 10; ++i_) *(float4*)(d_ + i_ * 128) = r[i_]; }

        int buf = 0;
        STAGE_LOAD(0);
        STAGE_WRITE(0);

        for (int t0 = 0; t0 < mlen; t0 += SEG) {
            // checkpoint into LDS, then release flag (DS pipe is in-order
            // per wave; compiler barrier prevents source-level reordering)
            if (c < Kn) ckbuf[half][t0 >> 6][c] = mydp;
            __threadfence_block();
            __asm__ __volatile__("" ::: "memory");
            if (c == 0) *(volatile int*)&seg_done[half] = (t0 >> 6) + 1;

            STAGE_LOAD((t0 >> 6) + 1);   // prefetch next segment's emissions
            const float* ebl = &ebuf[buf][half][0];

            if (t0 + SEG <= lmin) {
                for (int tt = 0; tt < SEG; tt += 8) {
#pragma unroll
                    for (int u = 0; u < 8; ++u) {
                        const float e = ebl[(tt + u) * Kn + cc];
                        const float* base_ = &dp[half][0];
                        DP_CORE(base_)
                        mydp = best + e;
                        dp[half][c] = mydp;
                    }
                }
            } else {
                for (int tt = 0; tt < SEG; tt += 8) {
#pragma unroll
                    for (int u = 0; u < 8; ++u) {
                        const int t = t0 + tt + u;
                        const float e = ebl[(tt + u) * Kn + cc];
                        const float* base_ = &dp[half][0];
                        DP_CORE(base_)
                        float nd = best + e;
                        mydp = (t < len) ? nd : mydp;
                        dp[half][c] = mydp;
                    }
                }
            }
            STAGE_WRITE(buf ^ 1);
            buf ^= 1;
        }
        if (c < Kn) dpfin[b * Kn + c] = mydp;
        // release any engine still waiting on out-of-range segments
        __threadfence_block();
        if (c == 0) *(volatile int*)&seg_done[half] = 32;
#undef STAGE_LOAD
#undef STAGE_WRITE
    } else {
        // ===================== REC waves (trailing consumers) ===============
        const int rw = w - 1;                 // 0,1
        const int l = tid & 63;
        const int rhalf = l >> 5;
        const int rc = l & 31;
        const int cc = (rc < Kn) ? rc : (Kn - 1);
        const int b = blockIdx.x * 2 + rhalf;

        float Trow[Kn];
#pragma unroll
        for (int p = 0; p < Kn; ++p) Trow[p] = T[cc * Kn + p];

        const float* pbase = P + (size_t)b * Ln * Kn;
        int len = Ln + 1;                     // sentinel until flag 1 seen

        for (int s = rw; s < 32; s += 2) {    // engine (rw,rhalf): segs s%2==rw
            bool need = (s * SEG) < len;
            if (!__any(need)) break;
            // spin until this half's checkpoint s is published (or not needed)
            while (true) {
                int f = *(volatile int*)&seg_done[rhalf];
                if (__all((!need) || (f >= s + 1))) break;
                __builtin_amdgcn_s_sleep(8);
            }
            __asm__ __volatile__("" ::: "memory");
            if (len > Ln) {                   // first released iteration
                len = *(volatile int*)&s_len2[rhalf];
                need = (s * SEG) < len;
            }
            if (need) {
                const int t0 = s * SEG;
                float mydp = (rc < Kn) ? ckbuf[rhalf][s][rc] : NEGV;
                rdp[rw][rhalf][rc] = mydp;
                const float* prow = pbase + (size_t)t0 * Kn;

                float eb[8];
#pragma unroll
                for (int u = 0; u < 8; ++u) eb[u] = prow[u * Kn + cc];

                for (int tt = 0; tt < SEG; tt += 8) {
#pragma unroll
                    for (int u = 0; u < 8; ++u) {
                        const int t = t0 + tt + u;
                        const float e = eb[u];
                        const float* base_ = &rdp[rw][rhalf][0];
                        DP_CORE(base_)
                        float nd = best + e;
                        mydp = (t < len) ? nd : mydp;
                        rdp[rw][rhalf][rc] = mydp;

                        // first-index argmax (jnp.argmax tie-break)
                        int arg = Kn - 1;
#pragma unroll
                        for (int p = Kn - 2; p >= 0; --p)
                            arg = (cand[p] == best) ? p : arg;
                        if (rc < Kn)
                            rcbuf[rw][rhalf][(tt + u) * Kn + rc] = (unsigned char)arg;

                        int tn = tt + u + 8;
                        int tloc = (t0 + tn < Ln) ? tn : (Ln - 1 - t0);
                        eb[u] = prow[tloc * Kn + cc];
                    }
                }
                // bulk flush this segment's backpointers
                const int4* s4 = (const int4*)&rcbuf[rw][rhalf][0];
                int4* d4 = (int4*)(choice + (size_t)b * Ln * Kn + (size_t)t0 * Kn);
                for (int i = rc; i < (SEG * Kn) / 16; i += 32) d4[i] = s4[i];
            }
        }
    }
}

// ---------------------------------------------------------------------------
// Backtrace: unchanged (exact integer function-composition scan).
// ---------------------------------------------------------------------------
__global__ __launch_bounds__(384, 1) void crf_bwd(
    const float* __restrict__ T, const unsigned char* __restrict__ choice,
    const float* __restrict__ dpfin, const int* __restrict__ lens,
    int* __restrict__ out)
{
    __shared__ unsigned char comp[Ln * Kn];   // 38912 B
    __shared__ int vchain[17];
    __shared__ int s_last, s_len;

    const int b = blockIdx.x;
    const int tid = threadIdx.x;

    {
        const int4* src = (const int4*)(choice + (size_t)b * Ln * Kn);
        int4* dst = (int4*)comp;
        for (int i = tid; i < (Ln * Kn) / 16; i += 384) dst[i] = src[i];
    }
    if (tid == 0) {
        s_len = lens[b];
        float bestv = dpfin[b * Kn + 0] + T[PAD_IDn * Kn + 0];
        int bl = 0;
        for (int ci = 1; ci < Kn; ++ci) {
            float v = dpfin[b * Kn + ci] + T[PAD_IDn * Kn + ci];
            if (v > bestv) { bestv = v; bl = ci; }
        }
        s_last = bl;
    }
    __syncthreads();
    const int len = s_len;

    // Phase 1: suffix-compose within each 128-step chunk, in place.
    {
        const int wv = tid >> 6;
        const int lane = tid & 63;
        const int ch = wv * 3 + lane / Kn;
        const int c = lane % Kn;
        if (lane < 3 * Kn && ch < 16) {
            int cur = c;
            const int tb = ch * 128 + 127;
            for (int i = 0; i < 128; ++i) {
                const int t = tb - i;
                int nv = comp[t * Kn + cur];   // cur <= 18 always: in-bounds
                cur = (t < len) ? nv : cur;
                comp[t * Kn + c] = cur;
            }
        }
    }
    __syncthreads();

    // Phase 2: chunk-boundary chain
    if (tid == 0) {
        int v = s_last;
        vchain[16] = v;
        for (int ch = 15; ch >= 0; --ch) {
            v = comp[ch * 128 * Kn + v];
            vchain[ch] = v;
        }
    }
    __syncthreads();

    // Phase 3: emit path
    const int last = s_last;
    int* orow = out + (size_t)b * Ln;
    for (int t = tid; t < Ln; t += 384) {
        int val;
        if (t >= len) {
            val = -1;
        } else if (t == Ln - 1) {
            val = last;
        } else {
            const int tp = t + 1;
            const int vc = vchain[(tp >> 7) + 1];
            val = comp[tp * Kn + vc];
        }
        orow[t] = val;
    }
}

// ---------------------------------------------------------------------------
extern "C" void kernel_launch(void* const* d_in, const int* in_sizes, int n_in,
                              void* d_out, int out_size, void* d_ws, size_t ws_size,
                              hipStream_t stream)
{
    const float* P    = (const float*)d_in[0];
    const float* T    = (const float*)d_in[1];
    const int*   mask = (const int*)d_in[2];
    int* out = (int*)d_out;

    // workspace layout — same proven footprint; dpck no longer needed
    const size_t choice_bytes = (size_t)Bn * Ln * Kn;            // 19,922,944
    unsigned char* choice = (unsigned char*)d_ws;
    float* dpfin = (float*)((char*)d_ws + choice_bytes);         // 38,912 B
    int* lens = (int*)((char*)d_ws + choice_bytes + (size_t)Bn * Kn * 4);

    crf_fused<<<Bn / 2, 192, 0, stream>>>(P, T, mask, dpfin, lens, choice);
    crf_bwd<<<Bn, 384, 0, stream>>>(T, choice, dpfin, lens, out);
}